// Round 14
// baseline (123.759 us; speedup 1.0000x reference)
//
#include <hip/hip_runtime.h>
#include <hip/hip_bf16.h>

// Fused Swin window attention for MI355X (gfx950) — round 14: r9 + s_setprio.
// History: r9=116.5us (head-partition, 3 blocks/CU, clean counters). Four
// attempts to beat it structurally all failed:
//   r10 4-blocks/CU -> VGPR-cap spills; r11 dual-acc ILP -> AGPR spills;
//   r12 phase3/4 SW pipeline -> -4% (perturbs compiler schedule);
//   r13 scratch dbuf+deferred reads -> mild spills (acc live across GEMMs).
// Bank conflicts re-derived: 264/72-elem strides are 2-way aliased = free
// (m136); the 11.8M counter is inherent b128 phase structure. Closed.
// r14 = r9 VERBATIM + __builtin_amdgcn_s_setprio(1)/(0) around MFMA bursts
// (T5): 3 independent blocks/CU sit at different phases -> scheduler can
// favor matrix-feeding waves (m191 attn regime, +4-7%), zero reg/LDS cost.

typedef __attribute__((ext_vector_type(8))) short bf16x8;
typedef __attribute__((ext_vector_type(4))) float f32x4;

__device__ __forceinline__ f32x4 mfma16(bf16x8 a, bf16x8 b, f32x4 c) {
  return __builtin_amdgcn_mfma_f32_16x16x32_bf16(a, b, c, 0, 0, 0);
}

__device__ __forceinline__ unsigned short f2bf(float f) {
  __hip_bfloat16 h = __float2bfloat16(f);
  return *reinterpret_cast<unsigned short*>(&h);
}

__device__ __forceinline__ uint2 pack4(float a, float b, float c, float d) {
  union { unsigned short u[4]; uint2 v; } pk;
  pk.u[0] = f2bf(a); pk.u[1] = f2bf(b); pk.u[2] = f2bf(c); pk.u[3] = f2bf(d);
  return pk.v;
}

#define LOG2E 1.4426950408889634f
#define EXPSCALE (0.17677669529663687f * 1.4426950408889634f)

// LDS layout (ushort elements); row strides multiples of 8 elem (16B) for b128.
#define XO  264           // x / oh region row stride (64 rows)
#define RTS 40            // per-wave RT scratch row stride (32 rows used)
#define PS  72            // P scratch row stride (16 rows)
#define RT_ELEMS 1280     // per-wave scratch: 32x40 (covers P's 16x72=1152)
#define OFF_RT 16896      // 64*264
#define SMEM_ELTS 22016   // 16896 + 4*1280 = 44,032 B -> 3 blocks/CU

// Weight tiled layout: elem(n,k) -> ((((n>>4)*8+(k>>5))*4+((k>>3)&3))*16+(n&15))*8+(k&7)
__global__ void prep_kernel(const float* __restrict__ w_qkv,
                            const float* __restrict__ w_out,
                            const float* __restrict__ pos_emb,
                            unsigned short* __restrict__ wqkvT,
                            unsigned short* __restrict__ woutT,
                            float* __restrict__ bias64) {
  const int stride = gridDim.x * blockDim.x;
  const int tid = blockIdx.x * blockDim.x + threadIdx.x;
  for (int i = tid; i < 768 * 256; i += stride) {
    int n = i >> 8, k = i & 255;
    int off = ((((n >> 4) * 8 + (k >> 5)) * 4 + ((k >> 3) & 3)) * 16 + (n & 15)) * 8 + (k & 7);
    wqkvT[off] = f2bf(w_qkv[k * 768 + n]);
  }
  for (int i = tid; i < 256 * 256; i += stride) {
    int n = i >> 8, k = i & 255;
    int off = ((((n >> 4) * 8 + (k >> 5)) * 4 + ((k >> 3) & 3)) * 16 + (n & 15)) * 8 + (k & 7);
    woutT[off] = f2bf(w_out[k * 256 + n]);
  }
  for (int i = tid; i < 64 * 64; i += stride) {
    int a = i >> 6, b = i & 63;
    int d0 = (b >> 3) - (a >> 3) + 7;
    int d1 = (b & 7) - (a & 7) + 7;
    bias64[i] = pos_emb[d0 * 15 + d1] * LOG2E;   // pre-scaled for exp2
  }
}

// 64px x 32col GEMM slice. SWAP=true: acc = mfma(w, x) -> (feat row, px col).
// SWAP=false: acc = mfma(x, w) -> (px row, feat col).
// MFMA burst wrapped in setprio(1)/(0) (T5).
template <bool SWAP>
__device__ __forceinline__ void gemm32(f32x4 (&acc)[4][2],
                                       const unsigned short* __restrict__ a_lds,
                                       const unsigned short* __restrict__ wT,
                                       int col0, int l15, int lq) {
  const f32x4 zero4 = {0.f, 0.f, 0.f, 0.f};
#pragma unroll
  for (int rt = 0; rt < 4; ++rt)
#pragma unroll
    for (int ct = 0; ct < 2; ++ct) acc[rt][ct] = zero4;
#pragma unroll
  for (int kk = 0; kk < 8; ++kk) {
    bf16x8 a[4], b[2];
#pragma unroll
    for (int rt = 0; rt < 4; ++rt)
      a[rt] = *(const bf16x8*)&a_lds[(rt * 16 + l15) * XO + kk * 32 + lq * 8];
#pragma unroll
    for (int ct = 0; ct < 2; ++ct)
      b[ct] = *(const bf16x8*)&wT[((((col0 >> 4) + ct) * 8 + kk) * 4 + lq) * 128 + l15 * 8];
    __builtin_amdgcn_s_setprio(1);
#pragma unroll
    for (int rt = 0; rt < 4; ++rt)
#pragma unroll
      for (int ct = 0; ct < 2; ++ct)
        acc[rt][ct] = SWAP ? mfma16(b[ct], a[rt], acc[rt][ct])
                           : mfma16(a[rt], b[ct], acc[rt][ct]);
    __builtin_amdgcn_s_setprio(0);
  }
}

__global__ __launch_bounds__(256, 3)
void winattn_kernel(const float* __restrict__ x,
                    const unsigned short* __restrict__ wqkvT,
                    const unsigned short* __restrict__ woutT,
                    const float* __restrict__ bias64,
                    const float* __restrict__ b_out,
                    float* __restrict__ out) {
  __shared__ unsigned short smem[SMEM_ELTS];

  const int tid = threadIdx.x;
  const int lane = tid & 63;
  const int w = tid >> 6;
  const int l15 = lane & 15;
  const int lq = lane >> 4;

  const int bid = blockIdx.x;
  const int win = bid & 255;
  const int img = bid >> 8;
  const int wy = win >> 4, wx = win & 15;

  unsigned short* x_lds  = smem;                 // phase 1-2: x; phase 3-4: oh
  unsigned short* oh_lds = smem;
  unsigned short* rt_buf = smem + OFF_RT + w * RT_ELEMS;   // wave-private

  const f32x4 zero4 = {0.f, 0.f, 0.f, 0.f};
  const size_t img_base = (size_t)img * 128 * 128 * 256;

  // ---------- phase 1: stage x window -> bf16 LDS (coalesced) ----------
  {
#pragma unroll
    for (int r = 0; r < 16; ++r) {
      int p = r * 4 + w;                 // pixel 0..63
      const float* src = x + img_base +
          (((size_t)(wy * 8 + (p >> 3)) * 128) + (wx * 8 + (p & 7))) * 256 + lane * 4;
      float4 v4 = *(const float4*)src;
      *(uint2*)&x_lds[p * XO + lane * 4] = pack4(v4.x, v4.y, v4.z, v4.w);
    }
  }
  __syncthreads();   // bar1

  // ---------- phase 2: q/k/v for this wave's 2 heads (r9 verbatim) ----------
  // qf/kf[rt][hh]: A/B-frag, (px rt*16+l15, feat hh*32+lq*8..+8)
  // vf[ft][h2][hh]: A-frag of vT, (feat hh*32+ft*16+l15, kv px h2*32+lq*8..+8)
  bf16x8 qf[4][2], kf[4][2], vf[2][2][2];
  {
    f32x4 acc[4][2];
#pragma unroll
    for (int hh = 0; hh < 2; ++hh) {    // q chunk (swapped: feat rows, px cols)
      gemm32<true>(acc, x_lds, wqkvT, w * 64 + hh * 32, l15, lq);
#pragma unroll
      for (int h2 = 0; h2 < 2; ++h2) {  // px halves through RT scratch
#pragma unroll
        for (int rr = 0; rr < 2; ++rr)
#pragma unroll
          for (int ct = 0; ct < 2; ++ct)
            *(uint2*)&rt_buf[(rr * 16 + l15) * RTS + ct * 16 + lq * 4] =
                pack4(acc[h2 * 2 + rr][ct][0], acc[h2 * 2 + rr][ct][1],
                      acc[h2 * 2 + rr][ct][2], acc[h2 * 2 + rr][ct][3]);
#pragma unroll
        for (int rr = 0; rr < 2; ++rr)
          qf[h2 * 2 + rr][hh] = *(const bf16x8*)&rt_buf[(rr * 16 + l15) * RTS + lq * 8];
      }
    }
#pragma unroll
    for (int hh = 0; hh < 2; ++hh) {    // k chunk
      gemm32<true>(acc, x_lds, wqkvT, 256 + w * 64 + hh * 32, l15, lq);
#pragma unroll
      for (int h2 = 0; h2 < 2; ++h2) {
#pragma unroll
        for (int rr = 0; rr < 2; ++rr)
#pragma unroll
          for (int ct = 0; ct < 2; ++ct)
            *(uint2*)&rt_buf[(rr * 16 + l15) * RTS + ct * 16 + lq * 4] =
                pack4(acc[h2 * 2 + rr][ct][0], acc[h2 * 2 + rr][ct][1],
                      acc[h2 * 2 + rr][ct][2], acc[h2 * 2 + rr][ct][3]);
#pragma unroll
        for (int rr = 0; rr < 2; ++rr)
          kf[h2 * 2 + rr][hh] = *(const bf16x8*)&rt_buf[(rr * 16 + l15) * RTS + lq * 8];
      }
    }
#pragma unroll
    for (int hh = 0; hh < 2; ++hh) {    // v chunk (normal: px rows, feat cols)
      gemm32<false>(acc, x_lds, wqkvT, 512 + w * 64 + hh * 32, l15, lq);
#pragma unroll
      for (int h2 = 0; h2 < 2; ++h2) {  // kv-px halves; transpose via RT
#pragma unroll
        for (int rr = 0; rr < 2; ++rr)
#pragma unroll
          for (int ct = 0; ct < 2; ++ct)
            *(uint2*)&rt_buf[(ct * 16 + l15) * RTS + rr * 16 + lq * 4] =
                pack4(acc[h2 * 2 + rr][ct][0], acc[h2 * 2 + rr][ct][1],
                      acc[h2 * 2 + rr][ct][2], acc[h2 * 2 + rr][ct][3]);
#pragma unroll
        for (int ft = 0; ft < 2; ++ft)
          vf[ft][h2][hh] = *(const bf16x8*)&rt_buf[(ft * 16 + l15) * RTS + lq * 8];
      }
    }
  }
  __syncthreads();   // bar2: all x reads done -> oh region (overlays x) safe

  // ---------- phase 3: attention for heads {2w, 2w+1}, all 64 pixels ----------
#pragma unroll
  for (int it = 0; it < 4; ++it) {
    f32x4 bias4[4];
#pragma unroll
    for (int jt = 0; jt < 4; ++jt)
      bias4[jt] = *(const f32x4*)&bias64[(it * 16 + l15) * 64 + jt * 16 + lq * 4];
#pragma unroll
    for (int hh = 0; hh < 2; ++hh) {
      // S^T = mfma(k, q): D[kv jt*16+lq*4+r][q px it*16+l15]
      f32x4 s[4];
      __builtin_amdgcn_s_setprio(1);
#pragma unroll
      for (int jt = 0; jt < 4; ++jt)
        s[jt] = mfma16(kf[jt][hh], qf[it][hh], zero4);
      __builtin_amdgcn_s_setprio(0);
      // p = exp2(s*ES + bias); row-sum over kv (regs + lq lanes)
      float rs = 0.f;
#pragma unroll
      for (int jt = 0; jt < 4; ++jt)
#pragma unroll
        for (int r = 0; r < 4; ++r) {
          s[jt][r] = __builtin_amdgcn_exp2f(s[jt][r] * EXPSCALE + bias4[jt][r]);
          rs += s[jt][r];
        }
      rs += __shfl_xor(rs, 16);
      rs += __shfl_xor(rs, 32);
      const float rinv = __builtin_amdgcn_rcpf(rs);

      // P -> wave-private scratch (P[q l15][kv]), packed b64
#pragma unroll
      for (int jt = 0; jt < 4; ++jt)
        *(uint2*)&rt_buf[l15 * PS + jt * 16 + lq * 4] =
            pack4(s[jt][0], s[jt][1], s[jt][2], s[jt][3]);
      const bf16x8 ap0 = *(const bf16x8*)&rt_buf[l15 * PS + lq * 8];
      const bf16x8 ap1 = *(const bf16x8*)&rt_buf[l15 * PS + 32 + lq * 8];

      // oh^T = mfma(vT, P^T): D[feat ft*16+lq*4+r][q px it*16+l15]
      __builtin_amdgcn_s_setprio(1);
      f32x4 o0 = mfma16(vf[0][0][hh], ap0, zero4);
      o0 = mfma16(vf[0][1][hh], ap1, o0);
      f32x4 o1 = mfma16(vf[1][0][hh], ap0, zero4);
      o1 = mfma16(vf[1][1][hh], ap1, o1);
      __builtin_amdgcn_s_setprio(0);

      // normalize + stage oh (px-major shared region), packed b64
      *(uint2*)&oh_lds[(it * 16 + l15) * XO + w * 64 + hh * 32 + lq * 4] =
          pack4(o0[0] * rinv, o0[1] * rinv, o0[2] * rinv, o0[3] * rinv);
      *(uint2*)&oh_lds[(it * 16 + l15) * XO + w * 64 + hh * 32 + 16 + lq * 4] =
          pack4(o1[0] * rinv, o1[1] * rinv, o1[2] * rinv, o1[3] * rinv);
    }
  }
  __syncthreads();   // bar3: oh complete

  // ---------- phase 4: out-proj, one K=256 GEMM (swapped) + epilogue ----------
  {
    f32x4 ACC[4][4];
#pragma unroll
    for (int rt = 0; rt < 4; ++rt)
#pragma unroll
      for (int ct = 0; ct < 4; ++ct) ACC[rt][ct] = zero4;
#pragma unroll
    for (int kk = 0; kk < 8; ++kk) {
      bf16x8 a[4], b[4];
#pragma unroll
      for (int rt = 0; rt < 4; ++rt)
        a[rt] = *(const bf16x8*)&oh_lds[(rt * 16 + l15) * XO + kk * 32 + lq * 8];
#pragma unroll
      for (int ct = 0; ct < 4; ++ct)
        b[ct] = *(const bf16x8*)&woutT[(((w * 4 + ct) * 8 + kk) * 4 + lq) * 128 + l15 * 8];
      __builtin_amdgcn_s_setprio(1);
#pragma unroll
      for (int rt = 0; rt < 4; ++rt)
#pragma unroll
        for (int ct = 0; ct < 4; ++ct)
          ACC[rt][ct] = mfma16(b[ct], a[rt], ACC[rt][ct]);   // D[ofeat][px]
      __builtin_amdgcn_s_setprio(0);
    }
    // epilogue: D rows = ofeat w*64+ct*16+lq*4+r, cols = px rt*16+l15
#pragma unroll
    for (int rt = 0; rt < 4; ++rt) {
      const int p = rt * 16 + l15;
      float* orow = out + img_base +
          (((size_t)(wy * 8 + (p >> 3)) * 128) + (wx * 8 + (p & 7))) * 256;
#pragma unroll
      for (int ct = 0; ct < 4; ++ct) {
        const int n0 = w * 64 + ct * 16 + lq * 4;
        const f32x4 bo4 = *(const f32x4*)&b_out[n0];
        f32x4 st;
#pragma unroll
        for (int r = 0; r < 4; ++r) st[r] = ACC[rt][ct][r] + bo4[r];
        *(f32x4*)(orow + n0) = st;
      }
    }
  }
}

extern "C" void kernel_launch(void* const* d_in, const int* in_sizes, int n_in,
                              void* d_out, int out_size, void* d_ws, size_t ws_size,
                              hipStream_t stream) {
  const float* x       = (const float*)d_in[0];
  const float* w_qkv   = (const float*)d_in[1];
  const float* pos_emb = (const float*)d_in[2];
  const float* w_out   = (const float*)d_in[3];
  const float* b_out   = (const float*)d_in[4];
  float* out = (float*)d_out;

  unsigned short* wqkvT = (unsigned short*)d_ws;
  unsigned short* woutT = wqkvT + 768 * 256;
  float* bias64 = (float*)(woutT + 256 * 256);

  prep_kernel<<<96, 256, 0, stream>>>(w_qkv, w_out, pos_emb, wqkvT, woutT, bias64);
  winattn_kernel<<<2048, 256, 0, stream>>>(x, wqkvT, woutT, bias64, b_out, out);
}

// Round 15
// 123.400 us; speedup vs baseline: 1.0029x; 1.0029x over previous
//
#include <hip/hip_runtime.h>
#include <hip/hip_bf16.h>

// Fused Swin window attention for MI355X (gfx950) — round 15: cut LDS traffic.
// r14 post-mortem: five scheduling levers (4 blk/CU, dual-acc, SW-pipe, dbuf,
// setprio) all <=0 on r9. Arithmetic re-diagnosis: r9 issues ~264 b128 + 112
// b64 LDS ops/wave; at ~8cyc/b128 per CU across 12 waves that's ~30k of the
// ~35k cyc block-round -> the kernel is LDS-THROUGHPUT bound, not latency.
// r15 = r9 with phase-2 q and k chunks widened to ONE 64-col pass each
// (gemm64, acc[4][4]): full-x-tile passes 6 -> 4, A-frag reads 192 -> 128
// b128/wave (-25% of all b128 traffic). v stays 2x gemm32 (transpose RT +
// register cap: peak live ~140 < 170 budget at 3 waves/SIMD).
// Phases 1/3/4 are r9 VERBATIM (no setprio). LDS layout unchanged (44,032 B).

typedef __attribute__((ext_vector_type(8))) short bf16x8;
typedef __attribute__((ext_vector_type(4))) float f32x4;

__device__ __forceinline__ f32x4 mfma16(bf16x8 a, bf16x8 b, f32x4 c) {
  return __builtin_amdgcn_mfma_f32_16x16x32_bf16(a, b, c, 0, 0, 0);
}

__device__ __forceinline__ unsigned short f2bf(float f) {
  __hip_bfloat16 h = __float2bfloat16(f);
  return *reinterpret_cast<unsigned short*>(&h);
}

__device__ __forceinline__ uint2 pack4(float a, float b, float c, float d) {
  union { unsigned short u[4]; uint2 v; } pk;
  pk.u[0] = f2bf(a); pk.u[1] = f2bf(b); pk.u[2] = f2bf(c); pk.u[3] = f2bf(d);
  return pk.v;
}

#define LOG2E 1.4426950408889634f
#define EXPSCALE (0.17677669529663687f * 1.4426950408889634f)

// LDS layout (ushort elements); row strides multiples of 8 elem (16B) for b128.
#define XO  264           // x / oh region row stride (64 rows)
#define RTS 40            // v-transpose RT stride (32 rows used)
#define PS  72            // q/k RT + P stride (16 rows x 72 = 1152 <= 1280)
#define RT_ELEMS 1280     // per-wave scratch
#define OFF_RT 16896      // 64*264
#define SMEM_ELTS 22016   // 16896 + 4*1280 = 44,032 B -> 3 blocks/CU

// Weight tiled layout: elem(n,k) -> ((((n>>4)*8+(k>>5))*4+((k>>3)&3))*16+(n&15))*8+(k&7)
__global__ void prep_kernel(const float* __restrict__ w_qkv,
                            const float* __restrict__ w_out,
                            const float* __restrict__ pos_emb,
                            unsigned short* __restrict__ wqkvT,
                            unsigned short* __restrict__ woutT,
                            float* __restrict__ bias64) {
  const int stride = gridDim.x * blockDim.x;
  const int tid = blockIdx.x * blockDim.x + threadIdx.x;
  for (int i = tid; i < 768 * 256; i += stride) {
    int n = i >> 8, k = i & 255;
    int off = ((((n >> 4) * 8 + (k >> 5)) * 4 + ((k >> 3) & 3)) * 16 + (n & 15)) * 8 + (k & 7);
    wqkvT[off] = f2bf(w_qkv[k * 768 + n]);
  }
  for (int i = tid; i < 256 * 256; i += stride) {
    int n = i >> 8, k = i & 255;
    int off = ((((n >> 4) * 8 + (k >> 5)) * 4 + ((k >> 3) & 3)) * 16 + (n & 15)) * 8 + (k & 7);
    woutT[off] = f2bf(w_out[k * 256 + n]);
  }
  for (int i = tid; i < 64 * 64; i += stride) {
    int a = i >> 6, b = i & 63;
    int d0 = (b >> 3) - (a >> 3) + 7;
    int d1 = (b & 7) - (a & 7) + 7;
    bias64[i] = pos_emb[d0 * 15 + d1] * LOG2E;   // pre-scaled for exp2
  }
}

// 64px x 32col slice. SWAP=true: D[feat][px]; SWAP=false: D[px][feat].
template <bool SWAP>
__device__ __forceinline__ void gemm32(f32x4 (&acc)[4][2],
                                       const unsigned short* __restrict__ a_lds,
                                       const unsigned short* __restrict__ wT,
                                       int col0, int l15, int lq) {
  const f32x4 zero4 = {0.f, 0.f, 0.f, 0.f};
#pragma unroll
  for (int rt = 0; rt < 4; ++rt)
#pragma unroll
    for (int ct = 0; ct < 2; ++ct) acc[rt][ct] = zero4;
#pragma unroll
  for (int kk = 0; kk < 8; ++kk) {
    bf16x8 a[4], b[2];
#pragma unroll
    for (int rt = 0; rt < 4; ++rt)
      a[rt] = *(const bf16x8*)&a_lds[(rt * 16 + l15) * XO + kk * 32 + lq * 8];
#pragma unroll
    for (int ct = 0; ct < 2; ++ct)
      b[ct] = *(const bf16x8*)&wT[((((col0 >> 4) + ct) * 8 + kk) * 4 + lq) * 128 + l15 * 8];
#pragma unroll
    for (int rt = 0; rt < 4; ++rt)
#pragma unroll
      for (int ct = 0; ct < 2; ++ct)
        acc[rt][ct] = SWAP ? mfma16(b[ct], a[rt], acc[rt][ct])
                           : mfma16(a[rt], b[ct], acc[rt][ct]);
  }
}

// 64px x 64col slice in ONE pass over x (swapped: D[feat ct*16+lq*4+r][px rt*16+l15]).
// Halves the A-frag LDS traffic vs two gemm32 calls.
__device__ __forceinline__ void gemm64(f32x4 (&acc)[4][4],
                                       const unsigned short* __restrict__ a_lds,
                                       const unsigned short* __restrict__ wT,
                                       int col0, int l15, int lq) {
  const f32x4 zero4 = {0.f, 0.f, 0.f, 0.f};
#pragma unroll
  for (int rt = 0; rt < 4; ++rt)
#pragma unroll
    for (int ct = 0; ct < 4; ++ct) acc[rt][ct] = zero4;
#pragma unroll
  for (int kk = 0; kk < 8; ++kk) {
    bf16x8 a[4], b[4];
#pragma unroll
    for (int rt = 0; rt < 4; ++rt)
      a[rt] = *(const bf16x8*)&a_lds[(rt * 16 + l15) * XO + kk * 32 + lq * 8];
#pragma unroll
    for (int ct = 0; ct < 4; ++ct)
      b[ct] = *(const bf16x8*)&wT[((((col0 >> 4) + ct) * 8 + kk) * 4 + lq) * 128 + l15 * 8];
#pragma unroll
    for (int rt = 0; rt < 4; ++rt)
#pragma unroll
      for (int ct = 0; ct < 4; ++ct)
        acc[rt][ct] = mfma16(b[ct], a[rt], acc[rt][ct]);
  }
}

__global__ __launch_bounds__(256, 3)
void winattn_kernel(const float* __restrict__ x,
                    const unsigned short* __restrict__ wqkvT,
                    const unsigned short* __restrict__ woutT,
                    const float* __restrict__ bias64,
                    const float* __restrict__ b_out,
                    float* __restrict__ out) {
  __shared__ unsigned short smem[SMEM_ELTS];

  const int tid = threadIdx.x;
  const int lane = tid & 63;
  const int w = tid >> 6;
  const int l15 = lane & 15;
  const int lq = lane >> 4;

  const int bid = blockIdx.x;
  const int win = bid & 255;
  const int img = bid >> 8;
  const int wy = win >> 4, wx = win & 15;

  unsigned short* x_lds  = smem;                 // phase 1-2: x; phase 3-4: oh
  unsigned short* oh_lds = smem;
  unsigned short* rt_buf = smem + OFF_RT + w * RT_ELEMS;   // wave-private

  const f32x4 zero4 = {0.f, 0.f, 0.f, 0.f};
  const size_t img_base = (size_t)img * 128 * 128 * 256;

  // ---------- phase 1: stage x window -> bf16 LDS (coalesced) ----------
  {
#pragma unroll
    for (int r = 0; r < 16; ++r) {
      int p = r * 4 + w;                 // pixel 0..63
      const float* src = x + img_base +
          (((size_t)(wy * 8 + (p >> 3)) * 128) + (wx * 8 + (p & 7))) * 256 + lane * 4;
      float4 v4 = *(const float4*)src;
      *(uint2*)&x_lds[p * XO + lane * 4] = pack4(v4.x, v4.y, v4.z, v4.w);
    }
  }
  __syncthreads();   // bar1

  // ---------- phase 2: q/k/v for this wave's 2 heads ----------
  // qf/kf[rt][hh]: A/B-frag, (px rt*16+l15, feat hh*32+lq*8..+8)
  // vf[ft][h2][hh]: A-frag of vT, (feat hh*32+ft*16+l15, kv px h2*32+lq*8..+8)
  bf16x8 qf[4][2], kf[4][2], vf[2][2][2];
  {
    // q: ONE 64-col pass; RT per px-tile rt through 16x72 buffer
    f32x4 acc4[4][4];
    gemm64(acc4, x_lds, wqkvT, w * 64, l15, lq);
#pragma unroll
    for (int rt = 0; rt < 4; ++rt) {
#pragma unroll
      for (int ct = 0; ct < 4; ++ct)
        *(uint2*)&rt_buf[l15 * PS + ct * 16 + lq * 4] =
            pack4(acc4[rt][ct][0], acc4[rt][ct][1], acc4[rt][ct][2], acc4[rt][ct][3]);
      qf[rt][0] = *(const bf16x8*)&rt_buf[l15 * PS + lq * 8];
      qf[rt][1] = *(const bf16x8*)&rt_buf[l15 * PS + 32 + lq * 8];
    }
    // k: ONE 64-col pass
    gemm64(acc4, x_lds, wqkvT, 256 + w * 64, l15, lq);
#pragma unroll
    for (int rt = 0; rt < 4; ++rt) {
#pragma unroll
      for (int ct = 0; ct < 4; ++ct)
        *(uint2*)&rt_buf[l15 * PS + ct * 16 + lq * 4] =
            pack4(acc4[rt][ct][0], acc4[rt][ct][1], acc4[rt][ct][2], acc4[rt][ct][3]);
      kf[rt][0] = *(const bf16x8*)&rt_buf[l15 * PS + lq * 8];
      kf[rt][1] = *(const bf16x8*)&rt_buf[l15 * PS + 32 + lq * 8];
    }
  }
  {
    // v: two 32-col passes (normal orientation; transpose via 32-row RT)
    f32x4 acc[4][2];
#pragma unroll
    for (int hh = 0; hh < 2; ++hh) {
      gemm32<false>(acc, x_lds, wqkvT, 512 + w * 64 + hh * 32, l15, lq);
#pragma unroll
      for (int h2 = 0; h2 < 2; ++h2) {  // kv-px halves; transpose via RT
#pragma unroll
        for (int rr = 0; rr < 2; ++rr)
#pragma unroll
          for (int ct = 0; ct < 2; ++ct)
            *(uint2*)&rt_buf[(ct * 16 + l15) * RTS + rr * 16 + lq * 4] =
                pack4(acc[h2 * 2 + rr][ct][0], acc[h2 * 2 + rr][ct][1],
                      acc[h2 * 2 + rr][ct][2], acc[h2 * 2 + rr][ct][3]);
#pragma unroll
        for (int ft = 0; ft < 2; ++ft)
          vf[ft][h2][hh] = *(const bf16x8*)&rt_buf[(ft * 16 + l15) * RTS + lq * 8];
      }
    }
  }
  __syncthreads();   // bar2: all x reads done -> oh region (overlays x) safe

  // ---------- phase 3: attention for heads {2w, 2w+1}, all 64 pixels ----------
#pragma unroll
  for (int it = 0; it < 4; ++it) {
    f32x4 bias4[4];
#pragma unroll
    for (int jt = 0; jt < 4; ++jt)
      bias4[jt] = *(const f32x4*)&bias64[(it * 16 + l15) * 64 + jt * 16 + lq * 4];
#pragma unroll
    for (int hh = 0; hh < 2; ++hh) {
      // S^T = mfma(k, q): D[kv jt*16+lq*4+r][q px it*16+l15]
      f32x4 s[4];
#pragma unroll
      for (int jt = 0; jt < 4; ++jt)
        s[jt] = mfma16(kf[jt][hh], qf[it][hh], zero4);
      // p = exp2(s*ES + bias); row-sum over kv (regs + lq lanes)
      float rs = 0.f;
#pragma unroll
      for (int jt = 0; jt < 4; ++jt)
#pragma unroll
        for (int r = 0; r < 4; ++r) {
          s[jt][r] = __builtin_amdgcn_exp2f(s[jt][r] * EXPSCALE + bias4[jt][r]);
          rs += s[jt][r];
        }
      rs += __shfl_xor(rs, 16);
      rs += __shfl_xor(rs, 32);
      const float rinv = __builtin_amdgcn_rcpf(rs);

      // P -> wave-private scratch (P[q l15][kv]), packed b64
#pragma unroll
      for (int jt = 0; jt < 4; ++jt)
        *(uint2*)&rt_buf[l15 * PS + jt * 16 + lq * 4] =
            pack4(s[jt][0], s[jt][1], s[jt][2], s[jt][3]);
      const bf16x8 ap0 = *(const bf16x8*)&rt_buf[l15 * PS + lq * 8];
      const bf16x8 ap1 = *(const bf16x8*)&rt_buf[l15 * PS + 32 + lq * 8];

      // oh^T = mfma(vT, P^T): D[feat ft*16+lq*4+r][q px it*16+l15]
      f32x4 o0 = mfma16(vf[0][0][hh], ap0, zero4);
      o0 = mfma16(vf[0][1][hh], ap1, o0);
      f32x4 o1 = mfma16(vf[1][0][hh], ap0, zero4);
      o1 = mfma16(vf[1][1][hh], ap1, o1);

      // normalize + stage oh (px-major shared region), packed b64
      *(uint2*)&oh_lds[(it * 16 + l15) * XO + w * 64 + hh * 32 + lq * 4] =
          pack4(o0[0] * rinv, o0[1] * rinv, o0[2] * rinv, o0[3] * rinv);
      *(uint2*)&oh_lds[(it * 16 + l15) * XO + w * 64 + hh * 32 + 16 + lq * 4] =
          pack4(o1[0] * rinv, o1[1] * rinv, o1[2] * rinv, o1[3] * rinv);
    }
  }
  __syncthreads();   // bar3: oh complete

  // ---------- phase 4: out-proj, one K=256 GEMM (swapped) + epilogue ----------
  {
    f32x4 ACC[4][4];
#pragma unroll
    for (int rt = 0; rt < 4; ++rt)
#pragma unroll
      for (int ct = 0; ct < 4; ++ct) ACC[rt][ct] = zero4;
#pragma unroll
    for (int kk = 0; kk < 8; ++kk) {
      bf16x8 a[4], b[4];
#pragma unroll
      for (int rt = 0; rt < 4; ++rt)
        a[rt] = *(const bf16x8*)&oh_lds[(rt * 16 + l15) * XO + kk * 32 + lq * 8];
#pragma unroll
      for (int ct = 0; ct < 4; ++ct)
        b[ct] = *(const bf16x8*)&woutT[(((w * 4 + ct) * 8 + kk) * 4 + lq) * 128 + l15 * 8];
#pragma unroll
      for (int rt = 0; rt < 4; ++rt)
#pragma unroll
        for (int ct = 0; ct < 4; ++ct)
          ACC[rt][ct] = mfma16(b[ct], a[rt], ACC[rt][ct]);   // D[ofeat][px]
    }
    // epilogue: D rows = ofeat w*64+ct*16+lq*4+r, cols = px rt*16+l15
#pragma unroll
    for (int rt = 0; rt < 4; ++rt) {
      const int p = rt * 16 + l15;
      float* orow = out + img_base +
          (((size_t)(wy * 8 + (p >> 3)) * 128) + (wx * 8 + (p & 7))) * 256;
#pragma unroll
      for (int ct = 0; ct < 4; ++ct) {
        const int n0 = w * 64 + ct * 16 + lq * 4;
        const f32x4 bo4 = *(const f32x4*)&b_out[n0];
        f32x4 st;
#pragma unroll
        for (int r = 0; r < 4; ++r) st[r] = ACC[rt][ct][r] + bo4[r];
        *(f32x4*)(orow + n0) = st;
      }
    }
  }
}

extern "C" void kernel_launch(void* const* d_in, const int* in_sizes, int n_in,
                              void* d_out, int out_size, void* d_ws, size_t ws_size,
                              hipStream_t stream) {
  const float* x       = (const float*)d_in[0];
  const float* w_qkv   = (const float*)d_in[1];
  const float* pos_emb = (const float*)d_in[2];
  const float* w_out   = (const float*)d_in[3];
  const float* b_out   = (const float*)d_in[4];
  float* out = (float*)d_out;

  unsigned short* wqkvT = (unsigned short*)d_ws;
  unsigned short* woutT = wqkvT + 768 * 256;
  float* bias64 = (float*)(woutT + 256 * 256);

  prep_kernel<<<96, 256, 0, stream>>>(w_qkv, w_out, pos_emb, wqkvT, woutT, bias64);
  winattn_kernel<<<2048, 256, 0, stream>>>(x, wqkvT, woutT, bias64, b_out, out);
}

// Round 16
// 116.642 us; speedup vs baseline: 1.0610x; 1.0579x over previous
//
#include <hip/hip_runtime.h>
#include <hip/hip_bf16.h>

// Fused Swin window attention for MI355X (gfx950) — round 16: restore r9.
// r9 (head-partition, 3 blocks/CU, 44KB LDS) = 116.5us, the session best.
// Seven subsequent probes (r10-r15) all regressed or were neutral; the
// design space is closed: pixel-partition needs 64KB shared LDS (2 blk/CU),
// head-partition needs 96 fragment VGPRs (3 blk/CU max), 4 blk/CU infeasible
// in both regs and LDS. Residual is cross-pipe dependency latency (DS 44%,
// MFMA 26%, VALU 21% — none saturated) that 12 waves/CU partially overlap;
// per-block critical path ~35k cyc across all structures tried.
// This file is r9 byte-identical (final artifact).

typedef __attribute__((ext_vector_type(8))) short bf16x8;
typedef __attribute__((ext_vector_type(4))) float f32x4;

__device__ __forceinline__ f32x4 mfma16(bf16x8 a, bf16x8 b, f32x4 c) {
  return __builtin_amdgcn_mfma_f32_16x16x32_bf16(a, b, c, 0, 0, 0);
}

__device__ __forceinline__ unsigned short f2bf(float f) {
  __hip_bfloat16 h = __float2bfloat16(f);
  return *reinterpret_cast<unsigned short*>(&h);
}

__device__ __forceinline__ uint2 pack4(float a, float b, float c, float d) {
  union { unsigned short u[4]; uint2 v; } pk;
  pk.u[0] = f2bf(a); pk.u[1] = f2bf(b); pk.u[2] = f2bf(c); pk.u[3] = f2bf(d);
  return pk.v;
}

#define LOG2E 1.4426950408889634f
#define EXPSCALE (0.17677669529663687f * 1.4426950408889634f)

// LDS layout (ushort elements); row strides multiples of 8 elem (16B) for b128.
#define XO  264           // x / oh region row stride (64 rows)
#define RTS 40            // per-wave RT scratch row stride (32 rows used)
#define PS  72            // P scratch row stride (16 rows)
#define RT_ELEMS 1280     // per-wave scratch: 32x40 (covers P's 16x72=1152)
#define OFF_RT 16896      // 64*264
#define SMEM_ELTS 22016   // 16896 + 4*1280 = 44,032 B -> 3 blocks/CU

// Weight tiled layout: elem(n,k) -> ((((n>>4)*8+(k>>5))*4+((k>>3)&3))*16+(n&15))*8+(k&7)
__global__ void prep_kernel(const float* __restrict__ w_qkv,
                            const float* __restrict__ w_out,
                            const float* __restrict__ pos_emb,
                            unsigned short* __restrict__ wqkvT,
                            unsigned short* __restrict__ woutT,
                            float* __restrict__ bias64) {
  const int stride = gridDim.x * blockDim.x;
  const int tid = blockIdx.x * blockDim.x + threadIdx.x;
  for (int i = tid; i < 768 * 256; i += stride) {
    int n = i >> 8, k = i & 255;
    int off = ((((n >> 4) * 8 + (k >> 5)) * 4 + ((k >> 3) & 3)) * 16 + (n & 15)) * 8 + (k & 7);
    wqkvT[off] = f2bf(w_qkv[k * 768 + n]);
  }
  for (int i = tid; i < 256 * 256; i += stride) {
    int n = i >> 8, k = i & 255;
    int off = ((((n >> 4) * 8 + (k >> 5)) * 4 + ((k >> 3) & 3)) * 16 + (n & 15)) * 8 + (k & 7);
    woutT[off] = f2bf(w_out[k * 256 + n]);
  }
  for (int i = tid; i < 64 * 64; i += stride) {
    int a = i >> 6, b = i & 63;
    int d0 = (b >> 3) - (a >> 3) + 7;
    int d1 = (b & 7) - (a & 7) + 7;
    bias64[i] = pos_emb[d0 * 15 + d1] * LOG2E;   // pre-scaled for exp2
  }
}

// 64px x 32col GEMM slice. SWAP=true: acc = mfma(w, x) -> (feat row, px col).
// SWAP=false: acc = mfma(x, w) -> (px row, feat col). No explicit pipelining.
template <bool SWAP>
__device__ __forceinline__ void gemm32(f32x4 (&acc)[4][2],
                                       const unsigned short* __restrict__ a_lds,
                                       const unsigned short* __restrict__ wT,
                                       int col0, int l15, int lq) {
  const f32x4 zero4 = {0.f, 0.f, 0.f, 0.f};
#pragma unroll
  for (int rt = 0; rt < 4; ++rt)
#pragma unroll
    for (int ct = 0; ct < 2; ++ct) acc[rt][ct] = zero4;
#pragma unroll
  for (int kk = 0; kk < 8; ++kk) {
    bf16x8 a[4], b[2];
#pragma unroll
    for (int rt = 0; rt < 4; ++rt)
      a[rt] = *(const bf16x8*)&a_lds[(rt * 16 + l15) * XO + kk * 32 + lq * 8];
#pragma unroll
    for (int ct = 0; ct < 2; ++ct)
      b[ct] = *(const bf16x8*)&wT[((((col0 >> 4) + ct) * 8 + kk) * 4 + lq) * 128 + l15 * 8];
#pragma unroll
    for (int rt = 0; rt < 4; ++rt)
#pragma unroll
      for (int ct = 0; ct < 2; ++ct)
        acc[rt][ct] = SWAP ? mfma16(b[ct], a[rt], acc[rt][ct])
                           : mfma16(a[rt], b[ct], acc[rt][ct]);
  }
}

__global__ __launch_bounds__(256, 3)
void winattn_kernel(const float* __restrict__ x,
                    const unsigned short* __restrict__ wqkvT,
                    const unsigned short* __restrict__ woutT,
                    const float* __restrict__ bias64,
                    const float* __restrict__ b_out,
                    float* __restrict__ out) {
  __shared__ unsigned short smem[SMEM_ELTS];

  const int tid = threadIdx.x;
  const int lane = tid & 63;
  const int w = tid >> 6;
  const int l15 = lane & 15;
  const int lq = lane >> 4;

  const int bid = blockIdx.x;
  const int win = bid & 255;
  const int img = bid >> 8;
  const int wy = win >> 4, wx = win & 15;

  unsigned short* x_lds  = smem;                 // phase 1-2: x; phase 3-4: oh
  unsigned short* oh_lds = smem;
  unsigned short* rt_buf = smem + OFF_RT + w * RT_ELEMS;   // wave-private

  const f32x4 zero4 = {0.f, 0.f, 0.f, 0.f};
  const size_t img_base = (size_t)img * 128 * 128 * 256;

  // ---------- phase 1: stage x window -> bf16 LDS (coalesced) ----------
  {
#pragma unroll
    for (int r = 0; r < 16; ++r) {
      int p = r * 4 + w;                 // pixel 0..63
      const float* src = x + img_base +
          (((size_t)(wy * 8 + (p >> 3)) * 128) + (wx * 8 + (p & 7))) * 256 + lane * 4;
      float4 v4 = *(const float4*)src;
      *(uint2*)&x_lds[p * XO + lane * 4] = pack4(v4.x, v4.y, v4.z, v4.w);
    }
  }
  __syncthreads();   // bar1

  // ---------- phase 2: q/k/v for this wave's 2 heads, all wave-local ----------
  // qf/kf[rt][hh]: A/B-frag, (px rt*16+l15, feat hh*32+lq*8..+8)
  // vf[ft][h2][hh]: A-frag of vT, (feat hh*32+ft*16+l15, kv px h2*32+lq*8..+8)
  bf16x8 qf[4][2], kf[4][2], vf[2][2][2];
  {
    f32x4 acc[4][2];
#pragma unroll
    for (int hh = 0; hh < 2; ++hh) {    // q chunk (swapped: feat rows, px cols)
      gemm32<true>(acc, x_lds, wqkvT, w * 64 + hh * 32, l15, lq);
#pragma unroll
      for (int h2 = 0; h2 < 2; ++h2) {  // px halves through RT scratch
#pragma unroll
        for (int rr = 0; rr < 2; ++rr)
#pragma unroll
          for (int ct = 0; ct < 2; ++ct)
            *(uint2*)&rt_buf[(rr * 16 + l15) * RTS + ct * 16 + lq * 4] =
                pack4(acc[h2 * 2 + rr][ct][0], acc[h2 * 2 + rr][ct][1],
                      acc[h2 * 2 + rr][ct][2], acc[h2 * 2 + rr][ct][3]);
#pragma unroll
        for (int rr = 0; rr < 2; ++rr)
          qf[h2 * 2 + rr][hh] = *(const bf16x8*)&rt_buf[(rr * 16 + l15) * RTS + lq * 8];
      }
    }
#pragma unroll
    for (int hh = 0; hh < 2; ++hh) {    // k chunk
      gemm32<true>(acc, x_lds, wqkvT, 256 + w * 64 + hh * 32, l15, lq);
#pragma unroll
      for (int h2 = 0; h2 < 2; ++h2) {
#pragma unroll
        for (int rr = 0; rr < 2; ++rr)
#pragma unroll
          for (int ct = 0; ct < 2; ++ct)
            *(uint2*)&rt_buf[(rr * 16 + l15) * RTS + ct * 16 + lq * 4] =
                pack4(acc[h2 * 2 + rr][ct][0], acc[h2 * 2 + rr][ct][1],
                      acc[h2 * 2 + rr][ct][2], acc[h2 * 2 + rr][ct][3]);
#pragma unroll
        for (int rr = 0; rr < 2; ++rr)
          kf[h2 * 2 + rr][hh] = *(const bf16x8*)&rt_buf[(rr * 16 + l15) * RTS + lq * 8];
      }
    }
#pragma unroll
    for (int hh = 0; hh < 2; ++hh) {    // v chunk (normal: px rows, feat cols)
      gemm32<false>(acc, x_lds, wqkvT, 512 + w * 64 + hh * 32, l15, lq);
#pragma unroll
      for (int h2 = 0; h2 < 2; ++h2) {  // kv-px halves; transpose via RT
#pragma unroll
        for (int rr = 0; rr < 2; ++rr)
#pragma unroll
          for (int ct = 0; ct < 2; ++ct)
            *(uint2*)&rt_buf[(ct * 16 + l15) * RTS + rr * 16 + lq * 4] =
                pack4(acc[h2 * 2 + rr][ct][0], acc[h2 * 2 + rr][ct][1],
                      acc[h2 * 2 + rr][ct][2], acc[h2 * 2 + rr][ct][3]);
#pragma unroll
        for (int ft = 0; ft < 2; ++ft)
          vf[ft][h2][hh] = *(const bf16x8*)&rt_buf[(ft * 16 + l15) * RTS + lq * 8];
      }
    }
  }
  __syncthreads();   // bar2: all x reads done -> oh region (overlays x) safe

  // ---------- phase 3: attention for heads {2w, 2w+1}, all 64 pixels ----------
#pragma unroll
  for (int it = 0; it < 4; ++it) {
    f32x4 bias4[4];
#pragma unroll
    for (int jt = 0; jt < 4; ++jt)
      bias4[jt] = *(const f32x4*)&bias64[(it * 16 + l15) * 64 + jt * 16 + lq * 4];
#pragma unroll
    for (int hh = 0; hh < 2; ++hh) {
      // S^T = mfma(k, q): D[kv jt*16+lq*4+r][q px it*16+l15]
      f32x4 s[4];
#pragma unroll
      for (int jt = 0; jt < 4; ++jt)
        s[jt] = mfma16(kf[jt][hh], qf[it][hh], zero4);
      // p = exp2(s*ES + bias); row-sum over kv (regs + lq lanes)
      float rs = 0.f;
#pragma unroll
      for (int jt = 0; jt < 4; ++jt)
#pragma unroll
        for (int r = 0; r < 4; ++r) {
          s[jt][r] = __builtin_amdgcn_exp2f(s[jt][r] * EXPSCALE + bias4[jt][r]);
          rs += s[jt][r];
        }
      rs += __shfl_xor(rs, 16);
      rs += __shfl_xor(rs, 32);
      const float rinv = __builtin_amdgcn_rcpf(rs);

      // P -> wave-private scratch (P[q l15][kv]), packed b64
#pragma unroll
      for (int jt = 0; jt < 4; ++jt)
        *(uint2*)&rt_buf[l15 * PS + jt * 16 + lq * 4] =
            pack4(s[jt][0], s[jt][1], s[jt][2], s[jt][3]);
      const bf16x8 ap0 = *(const bf16x8*)&rt_buf[l15 * PS + lq * 8];
      const bf16x8 ap1 = *(const bf16x8*)&rt_buf[l15 * PS + 32 + lq * 8];

      // oh^T = mfma(vT, P^T): D[feat ft*16+lq*4+r][q px it*16+l15]
      f32x4 o0 = mfma16(vf[0][0][hh], ap0, zero4);
      o0 = mfma16(vf[0][1][hh], ap1, o0);
      f32x4 o1 = mfma16(vf[1][0][hh], ap0, zero4);
      o1 = mfma16(vf[1][1][hh], ap1, o1);

      // normalize + stage oh (px-major shared region), packed b64
      *(uint2*)&oh_lds[(it * 16 + l15) * XO + w * 64 + hh * 32 + lq * 4] =
          pack4(o0[0] * rinv, o0[1] * rinv, o0[2] * rinv, o0[3] * rinv);
      *(uint2*)&oh_lds[(it * 16 + l15) * XO + w * 64 + hh * 32 + 16 + lq * 4] =
          pack4(o1[0] * rinv, o1[1] * rinv, o1[2] * rinv, o1[3] * rinv);
    }
  }
  __syncthreads();   // bar3: oh complete

  // ---------- phase 4: out-proj, one K=256 GEMM (swapped) + epilogue ----------
  {
    f32x4 ACC[4][4];
#pragma unroll
    for (int rt = 0; rt < 4; ++rt)
#pragma unroll
      for (int ct = 0; ct < 4; ++ct) ACC[rt][ct] = zero4;
#pragma unroll
    for (int kk = 0; kk < 8; ++kk) {
      bf16x8 a[4], b[4];
#pragma unroll
      for (int rt = 0; rt < 4; ++rt)
        a[rt] = *(const bf16x8*)&oh_lds[(rt * 16 + l15) * XO + kk * 32 + lq * 8];
#pragma unroll
      for (int ct = 0; ct < 4; ++ct)
        b[ct] = *(const bf16x8*)&woutT[(((w * 4 + ct) * 8 + kk) * 4 + lq) * 128 + l15 * 8];
#pragma unroll
      for (int rt = 0; rt < 4; ++rt)
#pragma unroll
        for (int ct = 0; ct < 4; ++ct)
          ACC[rt][ct] = mfma16(b[ct], a[rt], ACC[rt][ct]);   // D[ofeat][px]
    }
    // epilogue: D rows = ofeat w*64+ct*16+lq*4+r, cols = px rt*16+l15
#pragma unroll
    for (int rt = 0; rt < 4; ++rt) {
      const int p = rt * 16 + l15;
      float* orow = out + img_base +
          (((size_t)(wy * 8 + (p >> 3)) * 128) + (wx * 8 + (p & 7))) * 256;
#pragma unroll
      for (int ct = 0; ct < 4; ++ct) {
        const int n0 = w * 64 + ct * 16 + lq * 4;
        const f32x4 bo4 = *(const f32x4*)&b_out[n0];
        f32x4 st;
#pragma unroll
        for (int r = 0; r < 4; ++r) st[r] = ACC[rt][ct][r] + bo4[r];
        *(f32x4*)(orow + n0) = st;
      }
    }
  }
}

extern "C" void kernel_launch(void* const* d_in, const int* in_sizes, int n_in,
                              void* d_out, int out_size, void* d_ws, size_t ws_size,
                              hipStream_t stream) {
  const float* x       = (const float*)d_in[0];
  const float* w_qkv   = (const float*)d_in[1];
  const float* pos_emb = (const float*)d_in[2];
  const float* w_out   = (const float*)d_in[3];
  const float* b_out   = (const float*)d_in[4];
  float* out = (float*)d_out;

  unsigned short* wqkvT = (unsigned short*)d_ws;
  unsigned short* woutT = wqkvT + 768 * 256;
  float* bias64 = (float*)(woutT + 256 * 256);

  prep_kernel<<<96, 256, 0, stream>>>(w_qkv, w_out, pos_emb, wqkvT, woutT, bias64);
  winattn_kernel<<<2048, 256, 0, stream>>>(x, wqkvT, woutT, bias64, b_out, out);
}